// Round 21
// baseline (132.432 us; speedup 1.0000x reference)
//
#include <hip/hip_runtime.h>

#define B_DIM 64
#define T_DIM 524288
#define D_FAC 16
#define NFR_TOT 2097152  // total frames (B*T/D)
#define LBLK 128         // frames per composed block
#define NB 256           // blocks per row
#define NBLK_TOT 16384   // total blocks (B*NB)
#define NCLS 129         // LBLK+1 slope classes
#define CSTR 132         // padded stride (floats) of one block map (16B-aligned)
#define PF 16            // K2 prefetch depth (blocks)
#define PADBLK 16        // consts tail pad (blocks) for prefetch overrun
#define EPSV 1e-7f
#define BIGC 1e30f

// 20*log10(2)
#define DB_PER_LOG2 6.0205999132796239f
// log2(10)/20
#define L2TEN_OVER20 0.16609640474436813f

__device__ __forceinline__ float sum_log2_4(float4 x) {
  return __log2f(fabsf(x.x) + EPSV) + __log2f(fabsf(x.y) + EPSV) +
         __log2f(fabsf(x.z) + EPSV) + __log2f(fabsf(x.w) + EPSV);
}

template <int CTRL, int RM>
__device__ __forceinline__ float fmin_dpp_step(float v) {
  int vi = __float_as_int(v);
  int sh = __builtin_amdgcn_update_dpp(vi, vi, CTRL, RM, 0xf, false);
  return fminf(v, __int_as_float(sh));
}

// full-wave sum reduce; result valid on lane 63. Zero-fill (bound_ctrl=1)
// row_shr steps, then masked row_bcast15/31 folds (out-of-mask lanes add 0).
__device__ __forceinline__ float wave_sum63(float v) {
#define ADD_DPP(CTRL, RM)                                                 \
  v += __int_as_float(__builtin_amdgcn_update_dpp(                        \
      0, __float_as_int(v), CTRL, RM, 0xf, true));
  ADD_DPP(0x111, 0xf)  // row_shr:1
  ADD_DPP(0x112, 0xf)  // row_shr:2
  ADD_DPP(0x114, 0xf)  // row_shr:4
  ADD_DPP(0x118, 0xf)  // row_shr:8  -> lane15 of each row = row sum
  ADD_DPP(0x142, 0xa)  // row_bcast:15 -> lane31 = rows0-1, lane63 = rows2-3
  ADD_DPP(0x143, 0xc)  // row_bcast:31 -> lane63 = all
#undef ADD_DPP
  return v;
}

// K1a: streaming per-frame gain. One thread per frame, pure memory stream
// (131 MB read at k3-like BW). Split from the DP (r20: mixed kernel ran at
// 57us vs ~22us memory floor -- DP VALU and HBM stream don't overlap well).
__global__ __launch_bounds__(256) void k1a_gain(
    const float* __restrict__ audio, const float* __restrict__ p_thr,
    const float* __restrict__ p_ratio, float* __restrict__ g_out) {
  const int fr = blockIdx.x * 256 + threadIdx.x;  // tiles [B][T/D] exactly
  const float thr = p_thr[0];
  const float gslope = (1.f / p_ratio[0]) - 1.f;
  const float4* ap = (const float4*)(audio + (size_t)fr * D_FAC);
  float s = sum_log2_4(ap[0]) + sum_log2_4(ap[1]) + sum_log2_4(ap[2]) +
            sum_log2_4(ap[3]);
  g_out[fr] = fminf(0.f, (s * (DB_PER_LOG2 / 16.f) - thr) * gslope);
}

// K1b: DP-only compose, one wave per 128-frame block, full occupancy.
// g read from L2/L3 (8.4 MB). Lane holds classes {2l, 2l+1}: class 2l
// needs 2l-1 (lane l-1's second slot -> one wave_shr:1 DPP); 2l+1 needs
// own 2l. Class 128 = all-attack LINEAR form (r19): (1-A) sum A^(127-t)g_t
// via weighted contributions + DPP add-reduce. unroll 4 + bounds(256,4)
// (r18 ERRATA: full unroll -> VGPR 200 -> 10% occupancy).
__global__ __launch_bounds__(256, 4) void k1b_compose(
    const float* __restrict__ g_in, const float* __restrict__ p_att,
    const float* __restrict__ p_rel, float* __restrict__ consts) {
  __shared__ float cab[4][256];  // per wave: [2t]=ca_t, [2t+1]=cr_t
  const int tid = threadIdx.x;
  const int lane = tid & 63;
  const int w = tid >> 6;
  const int gblk = blockIdx.x * 4 + w;  // 0..16383
  const float A = p_att[0], R = p_rel[0];
  const float oneA = 1.f - A, oneR = 1.f - R;

  const float g0 = g_in[(size_t)gblk * LBLK + lane];
  const float g1 = g_in[(size_t)gblk * LBLK + 64 + lane];

  // stage ca/cr for t=lane (g0) and t=64+lane (g1); same-wave ds order
  cab[w][2 * lane] = oneA * g0;
  cab[w][2 * lane + 1] = oneR * g0;
  cab[w][128 + 2 * lane] = oneA * g1;
  cab[w][128 + 2 * lane + 1] = oneR * g1;

  const float2* cp = (const float2*)cab[w];
  float c0 = (lane == 0) ? 0.f : BIGC;  // class 2l
  float c1 = BIGC;                      // class 2l+1
#pragma unroll 4
  for (int t = 0; t < LBLK; ++t) {
    float2 cc = cp[t];  // uniform address -> LDS broadcast
    float prev = __int_as_float(__builtin_amdgcn_update_dpp(
        __float_as_int(BIGC), __float_as_int(c1), 0x138 /*wave_shr:1*/, 0xf,
        0xf, false));  // c_old[2l-1]; lane0 -> BIGC (class -1)
    float n1 = fminf(fmaf(A, c0, cc.x), fmaf(R, c1, cc.y));
    float n0 = fminf(fmaf(A, prev, cc.x), fmaf(R, c0, cc.y));
    c1 = n1; c0 = n0;
  }

  // class 128 = all-attack linear form
  const float l2A = __log2f(A);
  float h = oneA * exp2f((float)(127 - lane) * l2A) * g0 +
            oneA * exp2f((float)(63 - lane) * l2A) * g1;
  float c128 = wave_sum63(h);  // valid on lane 63

  float* outp = consts + (size_t)gblk * CSTR;
  float2 pr; pr.x = c0; pr.y = c1;
  *(float2*)(outp + 2 * lane) = pr;
  if (lane == 63) outp[128] = c128;
}

// K2: serial scan, one wave per row, 256 steps. Lanes 0-14: classes
// 8l..8l+7 (two float4); lane 15: classes 120..127 + class 128 (scalar qc;
// other lanes get BIGC -> term never wins). Per step: 9 fma + min tree +
// 4 row_shr DPP stages (all within DPP row 0) + readlane(15). PF=16
// register prefetch. Lanes 16..63 mirror lane 15, garbage isolated in
// DPP rows 1-3 (row_shr never crosses row boundaries).
__global__ __launch_bounds__(64) void k2_scan(const float* __restrict__ consts,
                                              float* __restrict__ states,
                                              const float* __restrict__ p_att,
                                              const float* __restrict__ p_rel) {
  const int r = blockIdx.x;
  const int lane = threadIdx.x;
  const float A = p_att[0], R = p_rel[0];
  const int cls0 = (lane < 15) ? 8 * lane : 120;
  float s0 = 1.f;
  for (int i = 0; i < 128; ++i) s0 *= (i < cls0) ? A : R;  // A^cls0 R^(128-cls0)
  const float rAR = A / R;
  const float sl0 = s0, sl1 = sl0 * rAR, sl2 = sl1 * rAR, sl3 = sl2 * rAR,
              sl4 = sl3 * rAR, sl5 = sl4 * rAR, sl6 = sl5 * rAR,
              sl7 = sl6 * rAR;
  const float sl8 = sl7 * rAR;  // lane15: A^128; others harmless
  const int loff = (lane < 15) ? 8 * lane : 120;
  const bool is15 = (lane == 15);

  const float* base = consts + (size_t)r * NB * CSTR;
  float* st = states + r * NB;

  float4 qa[PF], qb[PF];
  float qc[PF];
#pragma unroll
  for (int u = 0; u < PF; ++u) {
    qa[u] = *(const float4*)(base + u * CSTR + loff);
    qb[u] = *(const float4*)(base + u * CSTR + loff + 4);
    float t = base[u * CSTR + 128];
    qc[u] = is15 ? t : BIGC;
  }

  float p = 0.f;
  for (int j = 0; j < 4; ++j) {       // 4 groups of 64 steps
    float sj = 0.f;                   // lane i holds state of block j*64+i
    for (int k = 0; k < 4; ++k) {     // 4 sub-groups of PF=16
#pragma unroll
      for (int u = 0; u < PF; ++u) {
        const int b2 = j * 64 + k * PF + u;
        const int i = k * PF + u;  // step within group (uniform)
        float f0 = fmaf(sl0, p, qa[u].x);
        float f1 = fmaf(sl1, p, qa[u].y);
        float f2 = fmaf(sl2, p, qa[u].z);
        float f3 = fmaf(sl3, p, qa[u].w);
        float f4 = fmaf(sl4, p, qb[u].x);
        float f5 = fmaf(sl5, p, qb[u].y);
        float f6 = fmaf(sl6, p, qb[u].z);
        float f7 = fmaf(sl7, p, qb[u].w);
        float f8 = fmaf(sl8, p, qc[u]);
        float m = fminf(fminf(fminf(f0, f1), fminf(f2, f3)),
                        fminf(fminf(f4, f5), fminf(fminf(f6, f7), f8)));
        m = fmin_dpp_step<0x111, 0xf>(m);  // row_shr:1
        m = fmin_dpp_step<0x112, 0xf>(m);  // row_shr:2
        m = fmin_dpp_step<0x114, 0xf>(m);  // row_shr:4
        m = fmin_dpp_step<0x118, 0xf>(m);  // row_shr:8 -> lane15 = min(0..15)
        sj = (lane == i) ? p : sj;  // state at START of block b2 (old p)
        p = __int_as_float(__builtin_amdgcn_readlane(__float_as_int(m), 15));
        // refill slot u for block b2+PF (tail reads hit pad; never consumed)
        qa[u] = *(const float4*)(base + (b2 + PF) * CSTR + loff);
        qb[u] = *(const float4*)(base + (b2 + PF) * CSTR + loff + 4);
        float t2 = base[(b2 + PF) * CSTR + 128];
        qc[u] = is15 ? t2 : BIGC;
      }
    }
    st[j * 64 + lane] = sj;
  }
}

// K3: one wave per 128-frame block; lane owns frames {b*128+lane,
// b*128+64+lane} (32 samples in regs); wave replays the 128-step
// recurrence from the block-start state; applies two gains.
// Plain float4 stores (r14 ERRATA: NT stores -> partial-line RMW at HBM).
__global__ __launch_bounds__(256) void k3_apply(
    const float* __restrict__ audio, const float* __restrict__ states,
    const float* __restrict__ p_thr, const float* __restrict__ p_ratio,
    const float* __restrict__ p_makeup, const float* __restrict__ p_att,
    const float* __restrict__ p_rel, float* __restrict__ out) {
  const int tid = threadIdx.x;
  const int lane = tid & 63;
  const int w = tid >> 6;
  const int gblk = blockIdx.x * 4 + w;  // 0..16383
  const int row = gblk >> 8;
  const int b = gblk & (NB - 1);
  const float thr = p_thr[0], ratio = p_ratio[0], mk = p_makeup[0];
  const float A = p_att[0], R = p_rel[0];
  const float oneA = 1.f - A, oneR = 1.f - R;
  const float gslope = (1.f / ratio) - 1.f;

  const size_t base0 =
      (size_t)row * T_DIM + (size_t)(b * LBLK + lane) * D_FAC;
  const float4* ap0 = (const float4*)(audio + base0);
  const float4* ap1 = (const float4*)(audio + base0 + 64 * D_FAC);
  float4 x0 = ap0[0], x1 = ap0[1], x2 = ap0[2], x3 = ap0[3];
  float4 x4 = ap1[0], x5 = ap1[1], x6 = ap1[2], x7 = ap1[3];
  float s0 = sum_log2_4(x0) + sum_log2_4(x1) + sum_log2_4(x2) + sum_log2_4(x3);
  float s1 = sum_log2_4(x4) + sum_log2_4(x5) + sum_log2_4(x6) + sum_log2_4(x7);
  float g0 = fminf(0.f, (s0 * (DB_PER_LOG2 / 16.f) - thr) * gslope);
  float g1 = fminf(0.f, (s1 * (DB_PER_LOG2 / 16.f) - thr) * gslope);

  float p = states[gblk];
  float m0 = 0.f, m1 = 0.f;
  const int gi0 = __float_as_int(g0), gi1 = __float_as_int(g1);
#pragma unroll
  for (int t = 0; t < 64; ++t) {
    float gt = __int_as_float(__builtin_amdgcn_readlane(gi0, t));
    p = fminf(fmaf(A, p, oneA * gt), fmaf(R, p, oneR * gt));
    m0 = (lane == t) ? p : m0;
  }
#pragma unroll
  for (int t = 0; t < 64; ++t) {
    float gt = __int_as_float(__builtin_amdgcn_readlane(gi1, t));
    p = fminf(fmaf(A, p, oneA * gt), fmaf(R, p, oneR * gt));
    m1 = (lane == t) ? p : m1;
  }
  float mult0 = exp2f((m0 + mk) * L2TEN_OVER20);
  float mult1 = exp2f((m1 + mk) * L2TEN_OVER20);
  float4* op0 = (float4*)(out + base0);
  float4* op1 = (float4*)(out + base0 + 64 * D_FAC);
  float4 y;
  y.x = x0.x * mult0; y.y = x0.y * mult0; y.z = x0.z * mult0; y.w = x0.w * mult0; op0[0] = y;
  y.x = x1.x * mult0; y.y = x1.y * mult0; y.z = x1.z * mult0; y.w = x1.w * mult0; op0[1] = y;
  y.x = x2.x * mult0; y.y = x2.y * mult0; y.z = x2.z * mult0; y.w = x2.w * mult0; op0[2] = y;
  y.x = x3.x * mult0; y.y = x3.y * mult0; y.z = x3.z * mult0; y.w = x3.w * mult0; op0[3] = y;
  y.x = x4.x * mult1; y.y = x4.y * mult1; y.z = x4.z * mult1; y.w = x4.w * mult1; op1[0] = y;
  y.x = x5.x * mult1; y.y = x5.y * mult1; y.z = x5.z * mult1; y.w = x5.w * mult1; op1[1] = y;
  y.x = x6.x * mult1; y.y = x6.y * mult1; y.z = x6.z * mult1; y.w = x6.w * mult1; op1[2] = y;
  y.x = x7.x * mult1; y.y = x7.y * mult1; y.z = x7.z * mult1; y.w = x7.w * mult1; op1[3] = y;
}

extern "C" void kernel_launch(void* const* d_in, const int* in_sizes, int n_in,
                              void* d_out, int out_size, void* d_ws,
                              size_t ws_size, hipStream_t stream) {
  const float* audio = (const float*)d_in[0];
  const float* thr = (const float*)d_in[1];
  const float* ratio = (const float*)d_in[2];
  const float* makeup = (const float*)d_in[3];
  const float* att = (const float*)d_in[4];
  const float* rel = (const float*)d_in[5];
  float* out = (float*)d_out;

  const size_t G_BYTES = (size_t)NFR_TOT * sizeof(float);  // 8.4 MB
  const size_t CONSTS_BYTES =
      (size_t)(NBLK_TOT + PADBLK) * CSTR * sizeof(float);  // ~8.7 MB
  const size_t STATES_BYTES = (size_t)NBLK_TOT * sizeof(float);  // 64 KB

  float* gbuf;
  float* consts;
  float* states;
  if (ws_size >= G_BYTES + CONSTS_BYTES + STATES_BYTES) {
    gbuf = (float*)d_ws;
    consts = (float*)((char*)d_ws + G_BYTES);
    states = (float*)((char*)d_ws + G_BYTES + CONSTS_BYTES);
  } else {
    // d_out (128 MB) as scratch for g + consts: both dead before K3, and
    // K3 overwrites every byte of d_out. states (64 KB) stays in d_ws.
    gbuf = (float*)d_out;
    consts = (float*)((char*)d_out + G_BYTES);
    states = (float*)d_ws;
  }

  hipLaunchKernelGGL(k1a_gain, dim3(8192), dim3(256), 0, stream, audio, thr,
                     ratio, gbuf);
  hipLaunchKernelGGL(k1b_compose, dim3(4096), dim3(256), 0, stream, gbuf, att,
                     rel, consts);
  hipLaunchKernelGGL(k2_scan, dim3(64), dim3(64), 0, stream, consts, states,
                     att, rel);
  hipLaunchKernelGGL(k3_apply, dim3(4096), dim3(256), 0, stream, audio, states,
                     thr, ratio, makeup, att, rel, out);
}

// Round 22
// 123.393 us; speedup vs baseline: 1.0733x; 1.0733x over previous
//
#include <hip/hip_runtime.h>

#define B_DIM 64
#define T_DIM 524288
#define D_FAC 16
#define LBLK 128         // frames per composed block
#define NB 256           // blocks per row
#define NBLK_TOT 16384   // total blocks (B*NB)
#define NCLS 129         // LBLK+1 slope classes
#define CSTR 132         // padded stride (floats) of one block map (16B-aligned)
#define PF 16            // K2 prefetch depth (blocks)
#define PADBLK 16        // consts tail pad (blocks) for prefetch overrun
#define EPSV 1e-7f
#define BIGC 1e30f

// 20*log10(2)
#define DB_PER_LOG2 6.0205999132796239f
// log2(10)/20
#define L2TEN_OVER20 0.16609640474436813f

__device__ __forceinline__ float sum_log2_4(float4 x) {
  return __log2f(fabsf(x.x) + EPSV) + __log2f(fabsf(x.y) + EPSV) +
         __log2f(fabsf(x.z) + EPSV) + __log2f(fabsf(x.w) + EPSV);
}

template <int CTRL, int RM>
__device__ __forceinline__ float fmin_dpp_step(float v) {
  int vi = __float_as_int(v);
  int sh = __builtin_amdgcn_update_dpp(vi, vi, CTRL, RM, 0xf, false);
  return fminf(v, __int_as_float(sh));
}

// full-wave sum reduce; result valid on lane 63. Zero-fill (bound_ctrl=1)
// row_shr steps, then masked row_bcast15/31 folds (out-of-mask lanes add 0).
__device__ __forceinline__ float wave_sum63(float v) {
#define ADD_DPP(CTRL, RM)                                                 \
  v += __int_as_float(__builtin_amdgcn_update_dpp(                        \
      0, __float_as_int(v), CTRL, RM, 0xf, true));
  ADD_DPP(0x111, 0xf)  // row_shr:1
  ADD_DPP(0x112, 0xf)  // row_shr:2
  ADD_DPP(0x114, 0xf)  // row_shr:4
  ADD_DPP(0x118, 0xf)  // row_shr:8  -> lane15 of each row = row sum
  ADD_DPP(0x142, 0xa)  // row_bcast:15 -> lane31 = rows0-1, lane63 = rows2-3
  ADD_DPP(0x143, 0xc)  // row_bcast:31 -> lane63 = all
#undef ADD_DPP
  return v;
}

// K1: one wave per 128-frame block (r20 structure -- r21 ERRATA: splitting
// the audio stream from the DP cost +14us; keep fused). DP loop with
// EXPLICIT 8-deep register circular prefetch of the (ca,cr) pairs: keeps
// >=8 uniform ds_read_b64 in flight so the 120cyc LDS latency never
// surfaces at unroll-group boundaries (suspected ~20us of k1's 57).
// cab padded to 272 floats: tail prefetches (t+8 up to 135) are in-bounds
// garbage, never consumed. unroll 8 keeps cbuf[t&7] statically indexed
// (rule #20). Class 128 = all-attack linear form (r19). bounds(256,4)
// (r18 ERRATA: full unroll -> VGPR 200 -> 10% occupancy).
__global__ __launch_bounds__(256, 4) void k1_compose(
    const float* __restrict__ audio, const float* __restrict__ p_thr,
    const float* __restrict__ p_ratio, const float* __restrict__ p_att,
    const float* __restrict__ p_rel, float* __restrict__ consts) {
  __shared__ float cab[4][272];  // per wave: [2t]=ca_t, [2t+1]=cr_t (+pad)
  const int tid = threadIdx.x;
  const int lane = tid & 63;
  const int w = tid >> 6;
  const int gblk = blockIdx.x * 4 + w;  // 0..16383
  const int row = gblk >> 8;
  const int b = gblk & (NB - 1);
  const float thr = p_thr[0];
  const float A = p_att[0], R = p_rel[0];
  const float oneA = 1.f - A, oneR = 1.f - R;
  const float gslope = (1.f / p_ratio[0]) - 1.f;

  const size_t base0 =
      (size_t)row * T_DIM + (size_t)(b * LBLK + lane) * D_FAC;
  const float4* ap0 = (const float4*)(audio + base0);
  const float4* ap1 = (const float4*)(audio + base0 + 64 * D_FAC);
  float4 x0 = ap0[0], x1 = ap0[1], x2 = ap0[2], x3 = ap0[3];
  float4 x4 = ap1[0], x5 = ap1[1], x6 = ap1[2], x7 = ap1[3];
  float s0 = sum_log2_4(x0) + sum_log2_4(x1) + sum_log2_4(x2) + sum_log2_4(x3);
  float s1 = sum_log2_4(x4) + sum_log2_4(x5) + sum_log2_4(x6) + sum_log2_4(x7);
  float g0 = fminf(0.f, (s0 * (DB_PER_LOG2 / 16.f) - thr) * gslope);
  float g1 = fminf(0.f, (s1 * (DB_PER_LOG2 / 16.f) - thr) * gslope);

  // stage ca/cr for t=lane (g0) and t=64+lane (g1); same-wave ds order
  cab[w][2 * lane] = oneA * g0;
  cab[w][2 * lane + 1] = oneR * g0;
  cab[w][128 + 2 * lane] = oneA * g1;
  cab[w][128 + 2 * lane + 1] = oneR * g1;

  const float2* cp = (const float2*)cab[w];
  float c0 = (lane == 0) ? 0.f : BIGC;  // class 2l
  float c1 = BIGC;                      // class 2l+1

  float2 cbuf[8];
#pragma unroll
  for (int u = 0; u < 8; ++u) cbuf[u] = cp[u];

#pragma unroll 8
  for (int t = 0; t < LBLK; ++t) {
    float2 cc = cbuf[t & 7];  // static index under unroll 8
    float prev = __int_as_float(__builtin_amdgcn_update_dpp(
        __float_as_int(BIGC), __float_as_int(c1), 0x138 /*wave_shr:1*/, 0xf,
        0xf, false));  // c_old[2l-1]; lane0 -> BIGC (class -1)
    float n1 = fminf(fmaf(A, c0, cc.x), fmaf(R, c1, cc.y));
    float n0 = fminf(fmaf(A, prev, cc.x), fmaf(R, c0, cc.y));
    c1 = n1; c0 = n0;
    cbuf[t & 7] = cp[t + 8];  // refill 8 ahead (pad keeps it in-bounds)
  }

  // class 128 = all-attack linear form
  const float l2A = __log2f(A);
  float h = oneA * exp2f((float)(127 - lane) * l2A) * g0 +
            oneA * exp2f((float)(63 - lane) * l2A) * g1;
  float c128 = wave_sum63(h);  // valid on lane 63

  float* outp = consts + (size_t)gblk * CSTR;
  float2 pr; pr.x = c0; pr.y = c1;
  *(float2*)(outp + 2 * lane) = pr;
  if (lane == 63) outp[128] = c128;
}

// K2: serial scan, one wave per row, 256 steps. Lanes 0-14: classes
// 8l..8l+7 (two float4); lane 15: classes 120..127 + class 128 (scalar qc;
// other lanes get BIGC -> term never wins). Per step: 9 fma + min tree +
// 4 row_shr DPP stages (all within DPP row 0) + readlane(15). PF=16
// register prefetch. Lanes 16..63 mirror lane 15, garbage isolated in
// DPP rows 1-3 (row_shr never crosses row boundaries).
__global__ __launch_bounds__(64) void k2_scan(const float* __restrict__ consts,
                                              float* __restrict__ states,
                                              const float* __restrict__ p_att,
                                              const float* __restrict__ p_rel) {
  const int r = blockIdx.x;
  const int lane = threadIdx.x;
  const float A = p_att[0], R = p_rel[0];
  const int cls0 = (lane < 15) ? 8 * lane : 120;
  float s0 = 1.f;
  for (int i = 0; i < 128; ++i) s0 *= (i < cls0) ? A : R;  // A^cls0 R^(128-cls0)
  const float rAR = A / R;
  const float sl0 = s0, sl1 = sl0 * rAR, sl2 = sl1 * rAR, sl3 = sl2 * rAR,
              sl4 = sl3 * rAR, sl5 = sl4 * rAR, sl6 = sl5 * rAR,
              sl7 = sl6 * rAR;
  const float sl8 = sl7 * rAR;  // lane15: A^128; others harmless
  const int loff = (lane < 15) ? 8 * lane : 120;
  const bool is15 = (lane == 15);

  const float* base = consts + (size_t)r * NB * CSTR;
  float* st = states + r * NB;

  float4 qa[PF], qb[PF];
  float qc[PF];
#pragma unroll
  for (int u = 0; u < PF; ++u) {
    qa[u] = *(const float4*)(base + u * CSTR + loff);
    qb[u] = *(const float4*)(base + u * CSTR + loff + 4);
    float t = base[u * CSTR + 128];
    qc[u] = is15 ? t : BIGC;
  }

  float p = 0.f;
  for (int j = 0; j < 4; ++j) {       // 4 groups of 64 steps
    float sj = 0.f;                   // lane i holds state of block j*64+i
    for (int k = 0; k < 4; ++k) {     // 4 sub-groups of PF=16
#pragma unroll
      for (int u = 0; u < PF; ++u) {
        const int b2 = j * 64 + k * PF + u;
        const int i = k * PF + u;  // step within group (uniform)
        float f0 = fmaf(sl0, p, qa[u].x);
        float f1 = fmaf(sl1, p, qa[u].y);
        float f2 = fmaf(sl2, p, qa[u].z);
        float f3 = fmaf(sl3, p, qa[u].w);
        float f4 = fmaf(sl4, p, qb[u].x);
        float f5 = fmaf(sl5, p, qb[u].y);
        float f6 = fmaf(sl6, p, qb[u].z);
        float f7 = fmaf(sl7, p, qb[u].w);
        float f8 = fmaf(sl8, p, qc[u]);
        float m = fminf(fminf(fminf(f0, f1), fminf(f2, f3)),
                        fminf(fminf(f4, f5), fminf(fminf(f6, f7), f8)));
        m = fmin_dpp_step<0x111, 0xf>(m);  // row_shr:1
        m = fmin_dpp_step<0x112, 0xf>(m);  // row_shr:2
        m = fmin_dpp_step<0x114, 0xf>(m);  // row_shr:4
        m = fmin_dpp_step<0x118, 0xf>(m);  // row_shr:8 -> lane15 = min(0..15)
        sj = (lane == i) ? p : sj;  // state at START of block b2 (old p)
        p = __int_as_float(__builtin_amdgcn_readlane(__float_as_int(m), 15));
        // refill slot u for block b2+PF (tail reads hit pad; never consumed)
        qa[u] = *(const float4*)(base + (b2 + PF) * CSTR + loff);
        qb[u] = *(const float4*)(base + (b2 + PF) * CSTR + loff + 4);
        float t2 = base[(b2 + PF) * CSTR + 128];
        qc[u] = is15 ? t2 : BIGC;
      }
    }
    st[j * 64 + lane] = sj;
  }
}

// K3: one wave per 128-frame block; lane owns frames {b*128+lane,
// b*128+64+lane} (32 samples in regs); wave replays the 128-step
// recurrence from the block-start state; applies two gains.
// Plain float4 stores (r14 ERRATA: NT stores -> partial-line RMW at HBM).
__global__ __launch_bounds__(256) void k3_apply(
    const float* __restrict__ audio, const float* __restrict__ states,
    const float* __restrict__ p_thr, const float* __restrict__ p_ratio,
    const float* __restrict__ p_makeup, const float* __restrict__ p_att,
    const float* __restrict__ p_rel, float* __restrict__ out) {
  const int tid = threadIdx.x;
  const int lane = tid & 63;
  const int w = tid >> 6;
  const int gblk = blockIdx.x * 4 + w;  // 0..16383
  const int row = gblk >> 8;
  const int b = gblk & (NB - 1);
  const float thr = p_thr[0], ratio = p_ratio[0], mk = p_makeup[0];
  const float A = p_att[0], R = p_rel[0];
  const float oneA = 1.f - A, oneR = 1.f - R;
  const float gslope = (1.f / ratio) - 1.f;

  const size_t base0 =
      (size_t)row * T_DIM + (size_t)(b * LBLK + lane) * D_FAC;
  const float4* ap0 = (const float4*)(audio + base0);
  const float4* ap1 = (const float4*)(audio + base0 + 64 * D_FAC);
  float4 x0 = ap0[0], x1 = ap0[1], x2 = ap0[2], x3 = ap0[3];
  float4 x4 = ap1[0], x5 = ap1[1], x6 = ap1[2], x7 = ap1[3];
  float s0 = sum_log2_4(x0) + sum_log2_4(x1) + sum_log2_4(x2) + sum_log2_4(x3);
  float s1 = sum_log2_4(x4) + sum_log2_4(x5) + sum_log2_4(x6) + sum_log2_4(x7);
  float g0 = fminf(0.f, (s0 * (DB_PER_LOG2 / 16.f) - thr) * gslope);
  float g1 = fminf(0.f, (s1 * (DB_PER_LOG2 / 16.f) - thr) * gslope);

  float p = states[gblk];
  float m0 = 0.f, m1 = 0.f;
  const int gi0 = __float_as_int(g0), gi1 = __float_as_int(g1);
#pragma unroll
  for (int t = 0; t < 64; ++t) {
    float gt = __int_as_float(__builtin_amdgcn_readlane(gi0, t));
    p = fminf(fmaf(A, p, oneA * gt), fmaf(R, p, oneR * gt));
    m0 = (lane == t) ? p : m0;
  }
#pragma unroll
  for (int t = 0; t < 64; ++t) {
    float gt = __int_as_float(__builtin_amdgcn_readlane(gi1, t));
    p = fminf(fmaf(A, p, oneA * gt), fmaf(R, p, oneR * gt));
    m1 = (lane == t) ? p : m1;
  }
  float mult0 = exp2f((m0 + mk) * L2TEN_OVER20);
  float mult1 = exp2f((m1 + mk) * L2TEN_OVER20);
  float4* op0 = (float4*)(out + base0);
  float4* op1 = (float4*)(out + base0 + 64 * D_FAC);
  float4 y;
  y.x = x0.x * mult0; y.y = x0.y * mult0; y.z = x0.z * mult0; y.w = x0.w * mult0; op0[0] = y;
  y.x = x1.x * mult0; y.y = x1.y * mult0; y.z = x1.z * mult0; y.w = x1.w * mult0; op0[1] = y;
  y.x = x2.x * mult0; y.y = x2.y * mult0; y.z = x2.z * mult0; y.w = x2.w * mult0; op0[2] = y;
  y.x = x3.x * mult0; y.y = x3.y * mult0; y.z = x3.z * mult0; y.w = x3.w * mult0; op0[3] = y;
  y.x = x4.x * mult1; y.y = x4.y * mult1; y.z = x4.z * mult1; y.w = x4.w * mult1; op1[0] = y;
  y.x = x5.x * mult1; y.y = x5.y * mult1; y.z = x5.z * mult1; y.w = x5.w * mult1; op1[1] = y;
  y.x = x6.x * mult1; y.y = x6.y * mult1; y.z = x6.z * mult1; y.w = x6.w * mult1; op1[2] = y;
  y.x = x7.x * mult1; y.y = x7.y * mult1; y.z = x7.z * mult1; y.w = x7.w * mult1; op1[3] = y;
}

extern "C" void kernel_launch(void* const* d_in, const int* in_sizes, int n_in,
                              void* d_out, int out_size, void* d_ws,
                              size_t ws_size, hipStream_t stream) {
  const float* audio = (const float*)d_in[0];
  const float* thr = (const float*)d_in[1];
  const float* ratio = (const float*)d_in[2];
  const float* makeup = (const float*)d_in[3];
  const float* att = (const float*)d_in[4];
  const float* rel = (const float*)d_in[5];
  float* out = (float*)d_out;

  const size_t CONSTS_BYTES =
      (size_t)(NBLK_TOT + PADBLK) * CSTR * sizeof(float);             // ~8.7 MB
  const size_t STATES_BYTES = (size_t)NBLK_TOT * sizeof(float);       // 64 KB

  float* consts;
  float* states;
  if (ws_size >= CONSTS_BYTES + STATES_BYTES) {
    consts = (float*)d_ws;
    states = (float*)((char*)d_ws + CONSTS_BYTES);
  } else {
    consts = (float*)d_out;
    states = (float*)d_ws;
  }

  hipLaunchKernelGGL(k1_compose, dim3(4096), dim3(256), 0, stream, audio, thr,
                     ratio, att, rel, consts);
  hipLaunchKernelGGL(k2_scan, dim3(64), dim3(64), 0, stream, consts, states,
                     att, rel);
  hipLaunchKernelGGL(k3_apply, dim3(4096), dim3(256), 0, stream, audio, states,
                     thr, ratio, makeup, att, rel, out);
}

// Round 23
// 120.570 us; speedup vs baseline: 1.0984x; 1.0234x over previous
//
#include <hip/hip_runtime.h>

#define B_DIM 64
#define T_DIM 524288
#define D_FAC 16
#define LBLK 128         // frames per composed block
#define NB 256           // blocks per row
#define NBLK_TOT 16384   // total blocks (B*NB)
#define NCLS 129         // LBLK+1 slope classes
#define CSTR 132         // padded stride (floats) of one block map (16B-aligned)
#define PF 16            // K2 prefetch depth (blocks)
#define PADBLK 16        // consts tail pad (blocks) for prefetch overrun
#define EPSV 1e-7f
#define BIGC 1e30f

// 20*log10(2)
#define DB_PER_LOG2 6.0205999132796239f
// log2(10)/20
#define L2TEN_OVER20 0.16609640474436813f

__device__ __forceinline__ float sum_log2_4(float4 x) {
  return __log2f(fabsf(x.x) + EPSV) + __log2f(fabsf(x.y) + EPSV) +
         __log2f(fabsf(x.z) + EPSV) + __log2f(fabsf(x.w) + EPSV);
}

template <int CTRL, int RM>
__device__ __forceinline__ float fmin_dpp_step(float v) {
  int vi = __float_as_int(v);
  int sh = __builtin_amdgcn_update_dpp(vi, vi, CTRL, RM, 0xf, false);
  return fminf(v, __int_as_float(sh));
}

// full-wave sum reduce; result valid on lane 63. Zero-fill (bound_ctrl=1)
// row_shr steps, then masked row_bcast15/31 folds (out-of-mask lanes add 0).
__device__ __forceinline__ float wave_sum63(float v) {
#define ADD_DPP(CTRL, RM)                                                 \
  v += __int_as_float(__builtin_amdgcn_update_dpp(                        \
      0, __float_as_int(v), CTRL, RM, 0xf, true));
  ADD_DPP(0x111, 0xf)  // row_shr:1
  ADD_DPP(0x112, 0xf)  // row_shr:2
  ADD_DPP(0x114, 0xf)  // row_shr:4
  ADD_DPP(0x118, 0xf)  // row_shr:8  -> lane15 of each row = row sum
  ADD_DPP(0x142, 0xa)  // row_bcast:15 -> lane31 = rows0-1, lane63 = rows2-3
  ADD_DPP(0x143, 0xc)  // row_bcast:31 -> lane63 = all
#undef ADD_DPP
  return v;
}

// K1: ILP-2 -- one wave composes TWO adjacent 128-frame blocks. r8/r20
// cross-round evidence: the DP runs ~4x slower than issue floor with OR
// without LDS in the loop -> dependent-chain (DPP hazard) bound. Two
// independent chains interleave so each chain's stalls are the other's
// issue slots; interleaved LDS layout feeds both chains with ONE
// ds_read_b128 per step (15 inst/step for 2 blocks vs 16 for 2x r20).
// r22 ERRATA: deeper LDS prefetch regressed (+5us) -- not memory-bound.
// Class 128 = all-attack linear form (r19). bounds(256,4) (r18 ERRATA).
__global__ __launch_bounds__(256, 4) void k1_compose(
    const float* __restrict__ audio, const float* __restrict__ p_thr,
    const float* __restrict__ p_ratio, const float* __restrict__ p_att,
    const float* __restrict__ p_rel, float* __restrict__ consts) {
  __shared__ float cab[4][512];  // per wave: t -> (caA,crA,caB,crB)
  const int tid = threadIdx.x;
  const int lane = tid & 63;
  const int w = tid >> 6;
  const int gpair = blockIdx.x * 4 + w;  // 0..8191
  const int gblkA = gpair * 2;           // even -> A,B share a row
  const int gblkB = gblkA + 1;
  const int row = gblkA >> 8;
  const int bA = gblkA & (NB - 1);
  const float thr = p_thr[0];
  const float A = p_att[0], R = p_rel[0];
  const float oneA = 1.f - A, oneR = 1.f - R;
  const float gslope = (1.f / p_ratio[0]) - 1.f;

  const size_t baseA =
      (size_t)row * T_DIM + (size_t)(bA * LBLK + lane) * D_FAC;
  const size_t baseB = baseA + (size_t)LBLK * D_FAC;

  float gA0, gA1, gB0, gB1;
  {
    const float4* ap0 = (const float4*)(audio + baseA);
    const float4* ap1 = (const float4*)(audio + baseA + 64 * D_FAC);
    float s0 = sum_log2_4(ap0[0]) + sum_log2_4(ap0[1]) + sum_log2_4(ap0[2]) +
               sum_log2_4(ap0[3]);
    float s1 = sum_log2_4(ap1[0]) + sum_log2_4(ap1[1]) + sum_log2_4(ap1[2]) +
               sum_log2_4(ap1[3]);
    gA0 = fminf(0.f, (s0 * (DB_PER_LOG2 / 16.f) - thr) * gslope);
    gA1 = fminf(0.f, (s1 * (DB_PER_LOG2 / 16.f) - thr) * gslope);
  }
  {
    const float4* ap0 = (const float4*)(audio + baseB);
    const float4* ap1 = (const float4*)(audio + baseB + 64 * D_FAC);
    float s0 = sum_log2_4(ap0[0]) + sum_log2_4(ap0[1]) + sum_log2_4(ap0[2]) +
               sum_log2_4(ap0[3]);
    float s1 = sum_log2_4(ap1[0]) + sum_log2_4(ap1[1]) + sum_log2_4(ap1[2]) +
               sum_log2_4(ap1[3]);
    gB0 = fminf(0.f, (s0 * (DB_PER_LOG2 / 16.f) - thr) * gslope);
    gB1 = fminf(0.f, (s1 * (DB_PER_LOG2 / 16.f) - thr) * gslope);
  }

  // stage interleaved: slot t = (caA,crA,caB,crB); same-wave ds order
  float4* st4 = (float4*)cab[w];
  float4 v0; v0.x = oneA * gA0; v0.y = oneR * gA0; v0.z = oneA * gB0; v0.w = oneR * gB0;
  float4 v1; v1.x = oneA * gA1; v1.y = oneR * gA1; v1.z = oneA * gB1; v1.w = oneR * gB1;
  st4[lane] = v0;
  st4[64 + lane] = v1;

  const float4* cp4 = (const float4*)cab[w];
  float cA0 = (lane == 0) ? 0.f : BIGC;  // block A, class 2l
  float cA1 = BIGC;                      // block A, class 2l+1
  float cB0 = (lane == 0) ? 0.f : BIGC;  // block B, class 2l
  float cB1 = BIGC;                      // block B, class 2l+1
#pragma unroll 4
  for (int t = 0; t < LBLK; ++t) {
    float4 cc = cp4[t];  // uniform address -> LDS broadcast, both blocks
    float prevA = __int_as_float(__builtin_amdgcn_update_dpp(
        __float_as_int(BIGC), __float_as_int(cA1), 0x138 /*wave_shr:1*/, 0xf,
        0xf, false));
    float prevB = __int_as_float(__builtin_amdgcn_update_dpp(
        __float_as_int(BIGC), __float_as_int(cB1), 0x138 /*wave_shr:1*/, 0xf,
        0xf, false));
    float nA1 = fminf(fmaf(A, cA0, cc.x), fmaf(R, cA1, cc.y));
    float nA0 = fminf(fmaf(A, prevA, cc.x), fmaf(R, cA0, cc.y));
    float nB1 = fminf(fmaf(A, cB0, cc.z), fmaf(R, cB1, cc.w));
    float nB0 = fminf(fmaf(A, prevB, cc.z), fmaf(R, cB0, cc.w));
    cA1 = nA1; cA0 = nA0; cB1 = nB1; cB0 = nB0;
  }

  // class 128 = all-attack linear form (weights shared across blocks)
  const float l2A = __log2f(A);
  const float wHi = oneA * exp2f((float)(127 - lane) * l2A);
  const float wLo = oneA * exp2f((float)(63 - lane) * l2A);
  float c128A = wave_sum63(wHi * gA0 + wLo * gA1);  // valid on lane 63
  float c128B = wave_sum63(wHi * gB0 + wLo * gB1);  // valid on lane 63

  float* outA = consts + (size_t)gblkA * CSTR;
  float* outB = consts + (size_t)gblkB * CSTR;
  float2 prA; prA.x = cA0; prA.y = cA1;
  float2 prB; prB.x = cB0; prB.y = cB1;
  *(float2*)(outA + 2 * lane) = prA;
  *(float2*)(outB + 2 * lane) = prB;
  if (lane == 63) {
    outA[128] = c128A;
    outB[128] = c128B;
  }
}

// K2: serial scan, one wave per row, 256 steps. Lanes 0-14: classes
// 8l..8l+7 (two float4); lane 15: classes 120..127 + class 128 (scalar qc;
// other lanes get BIGC -> term never wins). Per step: 9 fma + min tree +
// 4 row_shr DPP stages (all within DPP row 0) + readlane(15). PF=16
// register prefetch. Lanes 16..63 mirror lane 15, garbage isolated in
// DPP rows 1-3 (row_shr never crosses row boundaries).
__global__ __launch_bounds__(64) void k2_scan(const float* __restrict__ consts,
                                              float* __restrict__ states,
                                              const float* __restrict__ p_att,
                                              const float* __restrict__ p_rel) {
  const int r = blockIdx.x;
  const int lane = threadIdx.x;
  const float A = p_att[0], R = p_rel[0];
  const int cls0 = (lane < 15) ? 8 * lane : 120;
  float s0 = 1.f;
  for (int i = 0; i < 128; ++i) s0 *= (i < cls0) ? A : R;  // A^cls0 R^(128-cls0)
  const float rAR = A / R;
  const float sl0 = s0, sl1 = sl0 * rAR, sl2 = sl1 * rAR, sl3 = sl2 * rAR,
              sl4 = sl3 * rAR, sl5 = sl4 * rAR, sl6 = sl5 * rAR,
              sl7 = sl6 * rAR;
  const float sl8 = sl7 * rAR;  // lane15: A^128; others harmless
  const int loff = (lane < 15) ? 8 * lane : 120;
  const bool is15 = (lane == 15);

  const float* base = consts + (size_t)r * NB * CSTR;
  float* st = states + r * NB;

  float4 qa[PF], qb[PF];
  float qc[PF];
#pragma unroll
  for (int u = 0; u < PF; ++u) {
    qa[u] = *(const float4*)(base + u * CSTR + loff);
    qb[u] = *(const float4*)(base + u * CSTR + loff + 4);
    float t = base[u * CSTR + 128];
    qc[u] = is15 ? t : BIGC;
  }

  float p = 0.f;
  for (int j = 0; j < 4; ++j) {       // 4 groups of 64 steps
    float sj = 0.f;                   // lane i holds state of block j*64+i
    for (int k = 0; k < 4; ++k) {     // 4 sub-groups of PF=16
#pragma unroll
      for (int u = 0; u < PF; ++u) {
        const int b2 = j * 64 + k * PF + u;
        const int i = k * PF + u;  // step within group (uniform)
        float f0 = fmaf(sl0, p, qa[u].x);
        float f1 = fmaf(sl1, p, qa[u].y);
        float f2 = fmaf(sl2, p, qa[u].z);
        float f3 = fmaf(sl3, p, qa[u].w);
        float f4 = fmaf(sl4, p, qb[u].x);
        float f5 = fmaf(sl5, p, qb[u].y);
        float f6 = fmaf(sl6, p, qb[u].z);
        float f7 = fmaf(sl7, p, qb[u].w);
        float f8 = fmaf(sl8, p, qc[u]);
        float m = fminf(fminf(fminf(f0, f1), fminf(f2, f3)),
                        fminf(fminf(f4, f5), fminf(fminf(f6, f7), f8)));
        m = fmin_dpp_step<0x111, 0xf>(m);  // row_shr:1
        m = fmin_dpp_step<0x112, 0xf>(m);  // row_shr:2
        m = fmin_dpp_step<0x114, 0xf>(m);  // row_shr:4
        m = fmin_dpp_step<0x118, 0xf>(m);  // row_shr:8 -> lane15 = min(0..15)
        sj = (lane == i) ? p : sj;  // state at START of block b2 (old p)
        p = __int_as_float(__builtin_amdgcn_readlane(__float_as_int(m), 15));
        // refill slot u for block b2+PF (tail reads hit pad; never consumed)
        qa[u] = *(const float4*)(base + (b2 + PF) * CSTR + loff);
        qb[u] = *(const float4*)(base + (b2 + PF) * CSTR + loff + 4);
        float t2 = base[(b2 + PF) * CSTR + 128];
        qc[u] = is15 ? t2 : BIGC;
      }
    }
    st[j * 64 + lane] = sj;
  }
}

// K3: one wave per 128-frame block; lane owns frames {b*128+lane,
// b*128+64+lane} (32 samples in regs); wave replays the 128-step
// recurrence from the block-start state; applies two gains.
// Plain float4 stores (r14 ERRATA: NT stores -> partial-line RMW at HBM).
__global__ __launch_bounds__(256) void k3_apply(
    const float* __restrict__ audio, const float* __restrict__ states,
    const float* __restrict__ p_thr, const float* __restrict__ p_ratio,
    const float* __restrict__ p_makeup, const float* __restrict__ p_att,
    const float* __restrict__ p_rel, float* __restrict__ out) {
  const int tid = threadIdx.x;
  const int lane = tid & 63;
  const int w = tid >> 6;
  const int gblk = blockIdx.x * 4 + w;  // 0..16383
  const int row = gblk >> 8;
  const int b = gblk & (NB - 1);
  const float thr = p_thr[0], ratio = p_ratio[0], mk = p_makeup[0];
  const float A = p_att[0], R = p_rel[0];
  const float oneA = 1.f - A, oneR = 1.f - R;
  const float gslope = (1.f / ratio) - 1.f;

  const size_t base0 =
      (size_t)row * T_DIM + (size_t)(b * LBLK + lane) * D_FAC;
  const float4* ap0 = (const float4*)(audio + base0);
  const float4* ap1 = (const float4*)(audio + base0 + 64 * D_FAC);
  float4 x0 = ap0[0], x1 = ap0[1], x2 = ap0[2], x3 = ap0[3];
  float4 x4 = ap1[0], x5 = ap1[1], x6 = ap1[2], x7 = ap1[3];
  float s0 = sum_log2_4(x0) + sum_log2_4(x1) + sum_log2_4(x2) + sum_log2_4(x3);
  float s1 = sum_log2_4(x4) + sum_log2_4(x5) + sum_log2_4(x6) + sum_log2_4(x7);
  float g0 = fminf(0.f, (s0 * (DB_PER_LOG2 / 16.f) - thr) * gslope);
  float g1 = fminf(0.f, (s1 * (DB_PER_LOG2 / 16.f) - thr) * gslope);

  float p = states[gblk];
  float m0 = 0.f, m1 = 0.f;
  const int gi0 = __float_as_int(g0), gi1 = __float_as_int(g1);
#pragma unroll
  for (int t = 0; t < 64; ++t) {
    float gt = __int_as_float(__builtin_amdgcn_readlane(gi0, t));
    p = fminf(fmaf(A, p, oneA * gt), fmaf(R, p, oneR * gt));
    m0 = (lane == t) ? p : m0;
  }
#pragma unroll
  for (int t = 0; t < 64; ++t) {
    float gt = __int_as_float(__builtin_amdgcn_readlane(gi1, t));
    p = fminf(fmaf(A, p, oneA * gt), fmaf(R, p, oneR * gt));
    m1 = (lane == t) ? p : m1;
  }
  float mult0 = exp2f((m0 + mk) * L2TEN_OVER20);
  float mult1 = exp2f((m1 + mk) * L2TEN_OVER20);
  float4* op0 = (float4*)(out + base0);
  float4* op1 = (float4*)(out + base0 + 64 * D_FAC);
  float4 y;
  y.x = x0.x * mult0; y.y = x0.y * mult0; y.z = x0.z * mult0; y.w = x0.w * mult0; op0[0] = y;
  y.x = x1.x * mult0; y.y = x1.y * mult0; y.z = x1.z * mult0; y.w = x1.w * mult0; op0[1] = y;
  y.x = x2.x * mult0; y.y = x2.y * mult0; y.z = x2.z * mult0; y.w = x2.w * mult0; op0[2] = y;
  y.x = x3.x * mult0; y.y = x3.y * mult0; y.z = x3.z * mult0; y.w = x3.w * mult0; op0[3] = y;
  y.x = x4.x * mult1; y.y = x4.y * mult1; y.z = x4.z * mult1; y.w = x4.w * mult1; op1[0] = y;
  y.x = x5.x * mult1; y.y = x5.y * mult1; y.z = x5.z * mult1; y.w = x5.w * mult1; op1[1] = y;
  y.x = x6.x * mult1; y.y = x6.y * mult1; y.z = x6.z * mult1; y.w = x6.w * mult1; op1[2] = y;
  y.x = x7.x * mult1; y.y = x7.y * mult1; y.z = x7.z * mult1; y.w = x7.w * mult1; op1[3] = y;
}

extern "C" void kernel_launch(void* const* d_in, const int* in_sizes, int n_in,
                              void* d_out, int out_size, void* d_ws,
                              size_t ws_size, hipStream_t stream) {
  const float* audio = (const float*)d_in[0];
  const float* thr = (const float*)d_in[1];
  const float* ratio = (const float*)d_in[2];
  const float* makeup = (const float*)d_in[3];
  const float* att = (const float*)d_in[4];
  const float* rel = (const float*)d_in[5];
  float* out = (float*)d_out;

  const size_t CONSTS_BYTES =
      (size_t)(NBLK_TOT + PADBLK) * CSTR * sizeof(float);             // ~8.7 MB
  const size_t STATES_BYTES = (size_t)NBLK_TOT * sizeof(float);       // 64 KB

  float* consts;
  float* states;
  if (ws_size >= CONSTS_BYTES + STATES_BYTES) {
    consts = (float*)d_ws;
    states = (float*)((char*)d_ws + CONSTS_BYTES);
  } else {
    consts = (float*)d_out;
    states = (float*)d_ws;
  }

  hipLaunchKernelGGL(k1_compose, dim3(2048), dim3(256), 0, stream, audio, thr,
                     ratio, att, rel, consts);
  hipLaunchKernelGGL(k2_scan, dim3(64), dim3(64), 0, stream, consts, states,
                     att, rel);
  hipLaunchKernelGGL(k3_apply, dim3(4096), dim3(256), 0, stream, audio, states,
                     thr, ratio, makeup, att, rel, out);
}

// Round 24
// 117.876 us; speedup vs baseline: 1.1235x; 1.0229x over previous
//
#include <hip/hip_runtime.h>

#define B_DIM 64
#define T_DIM 524288
#define D_FAC 16
#define LBLK 128         // frames per composed block
#define NB 256           // blocks per row
#define NBLK_TOT 16384   // total blocks (B*NB)
#define NCLS 129         // LBLK+1 slope classes
#define CSTR 132         // padded stride (floats) of one block map (16B-aligned)
#define PF 16            // K2 prefetch depth (blocks)
#define PADBLK 16        // consts tail pad (blocks) for prefetch overrun
#define EPSV 1e-7f
#define BIGC 1e30f

// 20*log10(2)
#define DB_PER_LOG2 6.0205999132796239f
// log2(10)/20
#define L2TEN_OVER20 0.16609640474436813f

__device__ __forceinline__ float sum_log2_4(float4 x) {
  return __log2f(fabsf(x.x) + EPSV) + __log2f(fabsf(x.y) + EPSV) +
         __log2f(fabsf(x.z) + EPSV) + __log2f(fabsf(x.w) + EPSV);
}

template <int CTRL, int RM>
__device__ __forceinline__ float fmin_dpp_step(float v) {
  int vi = __float_as_int(v);
  int sh = __builtin_amdgcn_update_dpp(vi, vi, CTRL, RM, 0xf, false);
  return fminf(v, __int_as_float(sh));
}

// full-wave sum reduce; result valid on lane 63. Zero-fill (bound_ctrl=1)
// row_shr steps, then masked row_bcast15/31 folds (out-of-mask lanes add 0).
__device__ __forceinline__ float wave_sum63(float v) {
#define ADD_DPP(CTRL, RM)                                                 \
  v += __int_as_float(__builtin_amdgcn_update_dpp(                        \
      0, __float_as_int(v), CTRL, RM, 0xf, true));
  ADD_DPP(0x111, 0xf)  // row_shr:1
  ADD_DPP(0x112, 0xf)  // row_shr:2
  ADD_DPP(0x114, 0xf)  // row_shr:4
  ADD_DPP(0x118, 0xf)  // row_shr:8  -> lane15 of each row = row sum
  ADD_DPP(0x142, 0xa)  // row_bcast:15 -> lane31 = rows0-1, lane63 = rows2-3
  ADD_DPP(0x143, 0xc)  // row_bcast:31 -> lane63 = all
#undef ADD_DPP
  return v;
}

// K1: one wave per 128-frame block (r20 structure). This round's single
// change: __launch_bounds__(256, 8) -> VGPR cap 64, 8 waves/SIMD (2x TLP).
// Cross-round evidence: occupancy 2->4 waves/SIMD was -40us (r18->r19);
// ILP-2 (r23) and LDS prefetch (r22) were null/negative -> k1 is
// latency-bound with insufficient TLP, its ~57us = poorly-overlapped
// {HBM read ~20, VALU ~14, LDS waits ~20}. Prologue split into two
// 4xfloat4 batches to keep live set under the 64-VGPR cap (no spill).
// Class 128 = all-attack linear form (r19).
__global__ __launch_bounds__(256, 8) void k1_compose(
    const float* __restrict__ audio, const float* __restrict__ p_thr,
    const float* __restrict__ p_ratio, const float* __restrict__ p_att,
    const float* __restrict__ p_rel, float* __restrict__ consts) {
  __shared__ float cab[4][256];  // per wave: [2t]=ca_t, [2t+1]=cr_t
  const int tid = threadIdx.x;
  const int lane = tid & 63;
  const int w = tid >> 6;
  const int gblk = blockIdx.x * 4 + w;  // 0..16383
  const int row = gblk >> 8;
  const int b = gblk & (NB - 1);
  const float thr = p_thr[0];
  const float A = p_att[0], R = p_rel[0];
  const float oneA = 1.f - A, oneR = 1.f - R;
  const float gslope = (1.f / p_ratio[0]) - 1.f;

  const size_t base0 =
      (size_t)row * T_DIM + (size_t)(b * LBLK + lane) * D_FAC;

  // prologue in two batches: <=4 float4 live at once (fits 64-VGPR cap)
  float g0, g1;
  {
    const float4* ap0 = (const float4*)(audio + base0);
    float4 x0 = ap0[0], x1 = ap0[1], x2 = ap0[2], x3 = ap0[3];
    float s0 = sum_log2_4(x0) + sum_log2_4(x1) + sum_log2_4(x2) +
               sum_log2_4(x3);
    g0 = fminf(0.f, (s0 * (DB_PER_LOG2 / 16.f) - thr) * gslope);
  }
  {
    const float4* ap1 = (const float4*)(audio + base0 + 64 * D_FAC);
    float4 x4 = ap1[0], x5 = ap1[1], x6 = ap1[2], x7 = ap1[3];
    float s1 = sum_log2_4(x4) + sum_log2_4(x5) + sum_log2_4(x6) +
               sum_log2_4(x7);
    g1 = fminf(0.f, (s1 * (DB_PER_LOG2 / 16.f) - thr) * gslope);
  }

  // stage ca/cr for t=lane (g0) and t=64+lane (g1); same-wave ds order
  cab[w][2 * lane] = oneA * g0;
  cab[w][2 * lane + 1] = oneR * g0;
  cab[w][128 + 2 * lane] = oneA * g1;
  cab[w][128 + 2 * lane + 1] = oneR * g1;

  const float2* cp = (const float2*)cab[w];
  float c0 = (lane == 0) ? 0.f : BIGC;  // class 2l
  float c1 = BIGC;                      // class 2l+1
#pragma unroll 4
  for (int t = 0; t < LBLK; ++t) {
    float2 cc = cp[t];  // uniform address -> LDS broadcast
    float prev = __int_as_float(__builtin_amdgcn_update_dpp(
        __float_as_int(BIGC), __float_as_int(c1), 0x138 /*wave_shr:1*/, 0xf,
        0xf, false));  // c_old[2l-1]; lane0 -> BIGC (class -1)
    float n1 = fminf(fmaf(A, c0, cc.x), fmaf(R, c1, cc.y));
    float n0 = fminf(fmaf(A, prev, cc.x), fmaf(R, c0, cc.y));
    c1 = n1; c0 = n0;
  }

  // class 128 = all-attack linear form
  const float l2A = __log2f(A);
  float h = oneA * exp2f((float)(127 - lane) * l2A) * g0 +
            oneA * exp2f((float)(63 - lane) * l2A) * g1;
  float c128 = wave_sum63(h);  // valid on lane 63

  float* outp = consts + (size_t)gblk * CSTR;
  float2 pr; pr.x = c0; pr.y = c1;
  *(float2*)(outp + 2 * lane) = pr;
  if (lane == 63) outp[128] = c128;
}

// K2: serial scan, one wave per row, 256 steps. Lanes 0-14: classes
// 8l..8l+7 (two float4); lane 15: classes 120..127 + class 128 (scalar qc;
// other lanes get BIGC -> term never wins). Per step: 9 fma + min tree +
// 4 row_shr DPP stages (all within DPP row 0) + readlane(15). PF=16
// register prefetch. Lanes 16..63 mirror lane 15, garbage isolated in
// DPP rows 1-3 (row_shr never crosses row boundaries).
__global__ __launch_bounds__(64) void k2_scan(const float* __restrict__ consts,
                                              float* __restrict__ states,
                                              const float* __restrict__ p_att,
                                              const float* __restrict__ p_rel) {
  const int r = blockIdx.x;
  const int lane = threadIdx.x;
  const float A = p_att[0], R = p_rel[0];
  const int cls0 = (lane < 15) ? 8 * lane : 120;
  float s0 = 1.f;
  for (int i = 0; i < 128; ++i) s0 *= (i < cls0) ? A : R;  // A^cls0 R^(128-cls0)
  const float rAR = A / R;
  const float sl0 = s0, sl1 = sl0 * rAR, sl2 = sl1 * rAR, sl3 = sl2 * rAR,
              sl4 = sl3 * rAR, sl5 = sl4 * rAR, sl6 = sl5 * rAR,
              sl7 = sl6 * rAR;
  const float sl8 = sl7 * rAR;  // lane15: A^128; others harmless
  const int loff = (lane < 15) ? 8 * lane : 120;
  const bool is15 = (lane == 15);

  const float* base = consts + (size_t)r * NB * CSTR;
  float* st = states + r * NB;

  float4 qa[PF], qb[PF];
  float qc[PF];
#pragma unroll
  for (int u = 0; u < PF; ++u) {
    qa[u] = *(const float4*)(base + u * CSTR + loff);
    qb[u] = *(const float4*)(base + u * CSTR + loff + 4);
    float t = base[u * CSTR + 128];
    qc[u] = is15 ? t : BIGC;
  }

  float p = 0.f;
  for (int j = 0; j < 4; ++j) {       // 4 groups of 64 steps
    float sj = 0.f;                   // lane i holds state of block j*64+i
    for (int k = 0; k < 4; ++k) {     // 4 sub-groups of PF=16
#pragma unroll
      for (int u = 0; u < PF; ++u) {
        const int b2 = j * 64 + k * PF + u;
        const int i = k * PF + u;  // step within group (uniform)
        float f0 = fmaf(sl0, p, qa[u].x);
        float f1 = fmaf(sl1, p, qa[u].y);
        float f2 = fmaf(sl2, p, qa[u].z);
        float f3 = fmaf(sl3, p, qa[u].w);
        float f4 = fmaf(sl4, p, qb[u].x);
        float f5 = fmaf(sl5, p, qb[u].y);
        float f6 = fmaf(sl6, p, qb[u].z);
        float f7 = fmaf(sl7, p, qb[u].w);
        float f8 = fmaf(sl8, p, qc[u]);
        float m = fminf(fminf(fminf(f0, f1), fminf(f2, f3)),
                        fminf(fminf(f4, f5), fminf(fminf(f6, f7), f8)));
        m = fmin_dpp_step<0x111, 0xf>(m);  // row_shr:1
        m = fmin_dpp_step<0x112, 0xf>(m);  // row_shr:2
        m = fmin_dpp_step<0x114, 0xf>(m);  // row_shr:4
        m = fmin_dpp_step<0x118, 0xf>(m);  // row_shr:8 -> lane15 = min(0..15)
        sj = (lane == i) ? p : sj;  // state at START of block b2 (old p)
        p = __int_as_float(__builtin_amdgcn_readlane(__float_as_int(m), 15));
        // refill slot u for block b2+PF (tail reads hit pad; never consumed)
        qa[u] = *(const float4*)(base + (b2 + PF) * CSTR + loff);
        qb[u] = *(const float4*)(base + (b2 + PF) * CSTR + loff + 4);
        float t2 = base[(b2 + PF) * CSTR + 128];
        qc[u] = is15 ? t2 : BIGC;
      }
    }
    st[j * 64 + lane] = sj;
  }
}

// K3: one wave per 128-frame block; lane owns frames {b*128+lane,
// b*128+64+lane} (32 samples in regs); wave replays the 128-step
// recurrence from the block-start state; applies two gains.
// Plain float4 stores (r14 ERRATA: NT stores -> partial-line RMW at HBM).
__global__ __launch_bounds__(256) void k3_apply(
    const float* __restrict__ audio, const float* __restrict__ states,
    const float* __restrict__ p_thr, const float* __restrict__ p_ratio,
    const float* __restrict__ p_makeup, const float* __restrict__ p_att,
    const float* __restrict__ p_rel, float* __restrict__ out) {
  const int tid = threadIdx.x;
  const int lane = tid & 63;
  const int w = tid >> 6;
  const int gblk = blockIdx.x * 4 + w;  // 0..16383
  const int row = gblk >> 8;
  const int b = gblk & (NB - 1);
  const float thr = p_thr[0], ratio = p_ratio[0], mk = p_makeup[0];
  const float A = p_att[0], R = p_rel[0];
  const float oneA = 1.f - A, oneR = 1.f - R;
  const float gslope = (1.f / ratio) - 1.f;

  const size_t base0 =
      (size_t)row * T_DIM + (size_t)(b * LBLK + lane) * D_FAC;
  const float4* ap0 = (const float4*)(audio + base0);
  const float4* ap1 = (const float4*)(audio + base0 + 64 * D_FAC);
  float4 x0 = ap0[0], x1 = ap0[1], x2 = ap0[2], x3 = ap0[3];
  float4 x4 = ap1[0], x5 = ap1[1], x6 = ap1[2], x7 = ap1[3];
  float s0 = sum_log2_4(x0) + sum_log2_4(x1) + sum_log2_4(x2) + sum_log2_4(x3);
  float s1 = sum_log2_4(x4) + sum_log2_4(x5) + sum_log2_4(x6) + sum_log2_4(x7);
  float g0 = fminf(0.f, (s0 * (DB_PER_LOG2 / 16.f) - thr) * gslope);
  float g1 = fminf(0.f, (s1 * (DB_PER_LOG2 / 16.f) - thr) * gslope);

  float p = states[gblk];
  float m0 = 0.f, m1 = 0.f;
  const int gi0 = __float_as_int(g0), gi1 = __float_as_int(g1);
#pragma unroll
  for (int t = 0; t < 64; ++t) {
    float gt = __int_as_float(__builtin_amdgcn_readlane(gi0, t));
    p = fminf(fmaf(A, p, oneA * gt), fmaf(R, p, oneR * gt));
    m0 = (lane == t) ? p : m0;
  }
#pragma unroll
  for (int t = 0; t < 64; ++t) {
    float gt = __int_as_float(__builtin_amdgcn_readlane(gi1, t));
    p = fminf(fmaf(A, p, oneA * gt), fmaf(R, p, oneR * gt));
    m1 = (lane == t) ? p : m1;
  }
  float mult0 = exp2f((m0 + mk) * L2TEN_OVER20);
  float mult1 = exp2f((m1 + mk) * L2TEN_OVER20);
  float4* op0 = (float4*)(out + base0);
  float4* op1 = (float4*)(out + base0 + 64 * D_FAC);
  float4 y;
  y.x = x0.x * mult0; y.y = x0.y * mult0; y.z = x0.z * mult0; y.w = x0.w * mult0; op0[0] = y;
  y.x = x1.x * mult0; y.y = x1.y * mult0; y.z = x1.z * mult0; y.w = x1.w * mult0; op0[1] = y;
  y.x = x2.x * mult0; y.y = x2.y * mult0; y.z = x2.z * mult0; y.w = x2.w * mult0; op0[2] = y;
  y.x = x3.x * mult0; y.y = x3.y * mult0; y.z = x3.z * mult0; y.w = x3.w * mult0; op0[3] = y;
  y.x = x4.x * mult1; y.y = x4.y * mult1; y.z = x4.z * mult1; y.w = x4.w * mult1; op1[0] = y;
  y.x = x5.x * mult1; y.y = x5.y * mult1; y.z = x5.z * mult1; y.w = x5.w * mult1; op1[1] = y;
  y.x = x6.x * mult1; y.y = x6.y * mult1; y.z = x6.z * mult1; y.w = x6.w * mult1; op1[2] = y;
  y.x = x7.x * mult1; y.y = x7.y * mult1; y.z = x7.z * mult1; y.w = x7.w * mult1; op1[3] = y;
}

extern "C" void kernel_launch(void* const* d_in, const int* in_sizes, int n_in,
                              void* d_out, int out_size, void* d_ws,
                              size_t ws_size, hipStream_t stream) {
  const float* audio = (const float*)d_in[0];
  const float* thr = (const float*)d_in[1];
  const float* ratio = (const float*)d_in[2];
  const float* makeup = (const float*)d_in[3];
  const float* att = (const float*)d_in[4];
  const float* rel = (const float*)d_in[5];
  float* out = (float*)d_out;

  const size_t CONSTS_BYTES =
      (size_t)(NBLK_TOT + PADBLK) * CSTR * sizeof(float);             // ~8.7 MB
  const size_t STATES_BYTES = (size_t)NBLK_TOT * sizeof(float);       // 64 KB

  float* consts;
  float* states;
  if (ws_size >= CONSTS_BYTES + STATES_BYTES) {
    consts = (float*)d_ws;
    states = (float*)((char*)d_ws + CONSTS_BYTES);
  } else {
    consts = (float*)d_out;
    states = (float*)d_ws;
  }

  hipLaunchKernelGGL(k1_compose, dim3(4096), dim3(256), 0, stream, audio, thr,
                     ratio, att, rel, consts);
  hipLaunchKernelGGL(k2_scan, dim3(64), dim3(64), 0, stream, consts, states,
                     att, rel);
  hipLaunchKernelGGL(k3_apply, dim3(4096), dim3(256), 0, stream, audio, states,
                     thr, ratio, makeup, att, rel, out);
}